// Round 1
// baseline (841.642 us; speedup 1.0000x reference)
//
#include <hip/hip_runtime.h>
#include <cmath>

#define TT 1024
#define BB 8

// ---------------- K1: per-token per-head x @ {Wq,Wk,Wv} ----------------
__global__ __launch_bounds__(256) void k_xw(
    const float* __restrict__ x, const float* __restrict__ Wq,
    const float* __restrict__ Wk, const float* __restrict__ Wv,
    float* __restrict__ xqk, float* __restrict__ xv) {
  int bt = blockIdx.x;
  int tid = threadIdx.x;
  __shared__ float xs[256];
  __shared__ float wq[1024], wk[1024], wv[1024];
  xs[tid] = x[(size_t)bt * 256 + tid];
  for (int i = tid; i < 1024; i += 256) { wq[i] = Wq[i]; wk[i] = Wk[i]; wv[i] = Wv[i]; }
  __syncthreads();
  int h = tid >> 5, d = tid & 31;
  float aq = 0.f, ak = 0.f, av = 0.f;
#pragma unroll
  for (int e = 0; e < 32; ++e) {
    float xe = xs[h * 32 + e];
    aq = fmaf(xe, wq[e * 32 + d], aq);
    ak = fmaf(xe, wk[e * 32 + d], ak);
    av = fmaf(xe, wv[e * 32 + d], av);
  }
  xqk[(size_t)bt * 512 + tid] = aq;
  xqk[(size_t)bt * 512 + 256 + tid] = ak;
  xv[(size_t)bt * 256 + tid] = av;
}

// ---------------- K2: per b: [Q|K](l,c) = sum_t adj(l,t) * xqk(t,c) ----------------
// 128x128 tile, 8x8 register micro-tile, K-step 16.
__global__ __launch_bounds__(256) void k_gcn(
    const int* __restrict__ adj, const float* __restrict__ xqk,
    float* __restrict__ qs, float* __restrict__ ks) {
  __shared__ float a_s[16][132];   // [k][l], padded
  __shared__ float x_s[16][128];   // [k][c]
  int b = blockIdx.z;
  int lt = blockIdx.y * 128;
  int ct = blockIdx.x * 128;
  const int* A = adj + (size_t)b * TT * TT;
  const float* X = xqk + (size_t)b * TT * 512;
  int tid = threadIdx.x;
  int tx = tid & 15, ty = tid >> 4;
  float acc[8][8] = {};
  for (int kc = 0; kc < TT; kc += 16) {
#pragma unroll
    for (int i = 0; i < 2; ++i) {
      int e = tid + (i << 8);
      int l = e >> 2, kq = e & 3;
      int4 a4 = *(const int4*)&A[(size_t)(lt + l) * TT + kc + kq * 4];
      a_s[kq * 4 + 0][l] = (float)a4.x;
      a_s[kq * 4 + 1][l] = (float)a4.y;
      a_s[kq * 4 + 2][l] = (float)a4.z;
      a_s[kq * 4 + 3][l] = (float)a4.w;
      int k2 = e >> 5, c8 = e & 31;
      *(float4*)&x_s[k2][c8 * 4] =
          *(const float4*)&X[(size_t)(kc + k2) * 512 + ct + c8 * 4];
    }
    __syncthreads();
#pragma unroll
    for (int k = 0; k < 16; ++k) {
      float4 a0 = *(const float4*)&a_s[k][ty * 8];
      float4 a1 = *(const float4*)&a_s[k][ty * 8 + 4];
      float4 x0 = *(const float4*)&x_s[k][tx * 8];
      float4 x1 = *(const float4*)&x_s[k][tx * 8 + 4];
      float ar[8], xr[8];
      ar[0]=a0.x; ar[1]=a0.y; ar[2]=a0.z; ar[3]=a0.w;
      ar[4]=a1.x; ar[5]=a1.y; ar[6]=a1.z; ar[7]=a1.w;
      xr[0]=x0.x; xr[1]=x0.y; xr[2]=x0.z; xr[3]=x0.w;
      xr[4]=x1.x; xr[5]=x1.y; xr[6]=x1.z; xr[7]=x1.w;
#pragma unroll
      for (int ii = 0; ii < 8; ++ii)
#pragma unroll
        for (int jj = 0; jj < 8; ++jj)
          acc[ii][jj] = fmaf(ar[ii], xr[jj], acc[ii][jj]);
    }
    __syncthreads();
  }
#pragma unroll
  for (int i = 0; i < 8; ++i) {
    int l = lt + ty * 8 + i;
#pragma unroll
    for (int j4 = 0; j4 < 2; ++j4) {
      int c = ct + tx * 8 + j4 * 4;
      float4 o = make_float4(acc[i][j4*4+0], acc[i][j4*4+1], acc[i][j4*4+2], acc[i][j4*4+3]);
      if (c < 256)
        *(float4*)&qs[((size_t)b * TT + l) * 256 + c] = o;
      else
        *(float4*)&ks[((size_t)b * TT + l) * 256 + (c - 256)] = o;
    }
  }
}

// ---------------- K3: scores + leaky + Lam-mix + mask (raw) + online m/sum ----------------
// block = (b, 32 l-rows). threads: lg=tid>>5 (8 groups of 4 rows), h=(tid>>2)&7, tq=tid&3.
// Writes raw mixed/masked scores into the attn output region; m and 1/sum to ws.
__global__ __launch_bounds__(256, 1) void k_score(
    const float* __restrict__ qs, const float* __restrict__ ks,
    const int* __restrict__ adj, const float* __restrict__ Lam,
    float* __restrict__ sout, float* __restrict__ mrow, float* __restrict__ rrow) {
  __shared__ float k_s[16][256];           // xor-swizzled within each 8-float4 group
  __shared__ float sm_s[8 * 545 + 8];      // idx = h*545 + l*17 + t
  __shared__ float lam_s[64];
  int blk = blockIdx.x;
  int b = blk >> 5;
  int lt = (blk & 31) << 5;
  int tid = threadIdx.x;
  int lg = tid >> 5, h = (tid >> 2) & 7, tq = tid & 3;
  const float* QS = qs + (size_t)b * TT * 256;
  const float* KS = ks + (size_t)b * TT * 256;
  const int* AD = adj + (size_t)b * TT * TT;
  float* SO = sout + (size_t)b * 8 * TT * TT;
  if (tid < 64) lam_s[tid] = Lam[tid];
  float4 qr[4][8];
#pragma unroll
  for (int ll = 0; ll < 4; ++ll) {
    const float4* qp = (const float4*)&QS[(size_t)(lt + lg * 4 + ll) * 256 + h * 32];
#pragma unroll
    for (int i = 0; i < 8; ++i) qr[ll][i] = qp[i];
  }
  __syncthreads();
  float lamr[8];
#pragma unroll
  for (int j = 0; j < 8; ++j) lamr[j] = lam_s[h * 8 + j];
  float m[4], ssum[4];
#pragma unroll
  for (int ll = 0; ll < 4; ++ll) { m[ll] = -1e30f; ssum[ll] = 0.f; }
  int lanebase = (tid & 63) & 35;   // keep bit5 (row-group parity) and bits1:0 (tq)

  for (int tc = 0; tc < TT; tc += 16) {
    __syncthreads();   // protect k_s/sm_s from prior-iteration readers
#pragma unroll
    for (int i = 0; i < 4; ++i) {
      int e = tid + (i << 8);
      int t = e >> 6, c4 = e & 63;
      int hh = c4 >> 3, ii = c4 & 7;
      *(float4*)&k_s[t][(hh * 8 + (ii ^ hh)) * 4] =
          *(const float4*)&KS[(size_t)(tc + t) * 256 + c4 * 4];
    }
    __syncthreads();
#pragma unroll
    for (int st = 0; st < 4; ++st) {
      int t = tq + st * 4;
      float4 kv[8];
#pragma unroll
      for (int i = 0; i < 8; ++i)
        kv[i] = *(const float4*)&k_s[t][(h * 8 + (i ^ h)) * 4];
#pragma unroll
      for (int ll = 0; ll < 4; ++ll) {
        float acc = 0.f;
#pragma unroll
        for (int i = 0; i < 8; ++i) {
          acc = fmaf(qr[ll][i].x, kv[i].x, acc);
          acc = fmaf(qr[ll][i].y, kv[i].y, acc);
          acc = fmaf(qr[ll][i].z, kv[i].z, acc);
          acc = fmaf(qr[ll][i].w, kv[i].w, acc);
        }
        acc *= 0.0625f;
        float sraw = acc > 0.f ? acc : 0.01f * acc;
        float sm = 0.f;
#pragma unroll
        for (int j = 0; j < 8; ++j)
          sm = fmaf(lamr[j], __shfl(sraw, lanebase + (j << 2), 64), sm);
        int l = lg * 4 + ll;
        int a = AD[(size_t)(lt + l) * TT + tc + t];
        if (a > 0) {
          float mn = fmaxf(m[ll], sm);
          ssum[ll] = ssum[ll] * __expf(m[ll] - mn) + __expf(sm - mn);
          m[ll] = mn;
        } else {
          sm = -1e30f;
        }
        sm_s[h * 545 + l * 17 + t] = sm;
      }
    }
    __syncthreads();
    // coalesced writeout: 256 (h,l) rows x 16 t
    int col = tid & 15;
    int rbase = tid >> 4;
#pragma unroll
    for (int rr = 0; rr < 16; ++rr) {
      int r = rr * 16 + rbase;
      int hh = r >> 5, l = r & 31;
      SO[((size_t)hh * TT + lt + l) * TT + tc + col] = sm_s[hh * 545 + l * 17 + col];
    }
  }
  // combine partials across the 4 tq lanes
#pragma unroll
  for (int ll = 0; ll < 4; ++ll) {
    float mm = m[ll], ss = ssum[ll];
#pragma unroll
    for (int off = 1; off <= 2; off <<= 1) {
      float om = __shfl_xor(mm, off, 64);
      float os = __shfl_xor(ss, off, 64);
      float mn = fmaxf(mm, om);
      ss = ss * __expf(mm - mn) + os * __expf(om - mn);
      mm = mn;
    }
    m[ll] = mm; ssum[ll] = ss;
  }
  if (tq == 0) {
#pragma unroll
    for (int ll = 0; ll < 4; ++ll) {
      int l = lg * 4 + ll;
      size_t ridx = ((size_t)b * 8 + h) * TT + lt + l;
      mrow[ridx] = m[ll];
      rrow[ridx] = 1.f / ssum[ll];
    }
  }
}

// ---------------- K4: softmax finalize + PV + GELU ----------------
// block = (b, h, 256 l-rows). Reads raw scores from attn region, writes final
// softmax back, accumulates v = P @ xv with v-chunk in registers, GELU -> g.
__global__ __launch_bounds__(256, 1) void k_pv(
    float* __restrict__ attn, const float* __restrict__ xv,
    const float* __restrict__ mrow, const float* __restrict__ rrow,
    float* __restrict__ g) {
  __shared__ float p_s[256][36];   // [l][k], f4-group index xor-swizzled by (l>>3)&7
  __shared__ float v_s[32][36];    // [k][d]
  int b = blockIdx.z, h = blockIdx.y, lt = blockIdx.x * 256;
  int tid = threadIdx.x;
  int lth = tid >> 3, dth = tid & 7;
  float* AT = attn + ((size_t)(b * 8 + h) * TT + lt) * TT;
  const float* XV = xv + (size_t)b * TT * 256 + h * 32;
  size_t ridx0 = ((size_t)b * 8 + h) * TT + lt;
  float4 acc4[8];
#pragma unroll
  for (int i = 0; i < 8; ++i) acc4[i] = make_float4(0.f, 0.f, 0.f, 0.f);

  for (int tc = 0; tc < TT; tc += 32) {
#pragma unroll
    for (int i = 0; i < 8; ++i) {
      int e = tid + (i << 8);
      int row = e >> 3, kq = e & 7;
      size_t gi = (size_t)row * TT + tc + kq * 4;
      float4 s4 = *(const float4*)&AT[gi];
      float mm = mrow[ridx0 + row];
      float rr = rrow[ridx0 + row];
      float4 p4;
      p4.x = __expf(s4.x - mm) * rr;
      p4.y = __expf(s4.y - mm) * rr;
      p4.z = __expf(s4.z - mm) * rr;
      p4.w = __expf(s4.w - mm) * rr;
      *(float4*)&AT[gi] = p4;                                 // final attn out
      *(float4*)&p_s[row][((kq ^ ((row >> 3) & 7)) << 2)] = p4;
    }
    {
      int k = tid >> 3, dq = tid & 7;
      *(float4*)&v_s[k][dq * 4] = *(const float4*)&XV[(size_t)(tc + k) * 256 + dq * 4];
    }
    __syncthreads();
    float4 vreg[32];
#pragma unroll
    for (int k = 0; k < 32; ++k) vreg[k] = *(const float4*)&v_s[k][dth * 4];
    int sw = lth & 7;
#pragma unroll
    for (int ll = 0; ll < 8; ++ll) {
      int l = lth * 8 + ll;
      float4 a = acc4[ll];
#pragma unroll
      for (int kq = 0; kq < 8; ++kq) {
        float4 pp = *(const float4*)&p_s[l][((kq ^ sw) << 2)];
        float4 va = vreg[kq*4+0], vb = vreg[kq*4+1], vc = vreg[kq*4+2], vd = vreg[kq*4+3];
        a.x = fmaf(pp.x, va.x, a.x); a.x = fmaf(pp.y, vb.x, a.x);
        a.x = fmaf(pp.z, vc.x, a.x); a.x = fmaf(pp.w, vd.x, a.x);
        a.y = fmaf(pp.x, va.y, a.y); a.y = fmaf(pp.y, vb.y, a.y);
        a.y = fmaf(pp.z, vc.y, a.y); a.y = fmaf(pp.w, vd.y, a.y);
        a.z = fmaf(pp.x, va.z, a.z); a.z = fmaf(pp.y, vb.z, a.z);
        a.z = fmaf(pp.z, vc.z, a.z); a.z = fmaf(pp.w, vd.z, a.z);
        a.w = fmaf(pp.x, va.w, a.w); a.w = fmaf(pp.y, vb.w, a.w);
        a.w = fmaf(pp.z, vc.w, a.w); a.w = fmaf(pp.w, vd.w, a.w);
      }
      acc4[ll] = a;
    }
    __syncthreads();
  }
#pragma unroll
  for (int ll = 0; ll < 8; ++ll) {
    float4 v = acc4[ll];
    float4 ge;
    ge.x = 0.5f * v.x * (1.f + erff(v.x * 0.70710678118654752f));
    ge.y = 0.5f * v.y * (1.f + erff(v.y * 0.70710678118654752f));
    ge.z = 0.5f * v.z * (1.f + erff(v.z * 0.70710678118654752f));
    ge.w = 0.5f * v.w * (1.f + erff(v.w * 0.70710678118654752f));
    *(float4*)&g[((size_t)b * TT + lt + lth * 8 + ll) * 256 + h * 32 + dth * 4] = ge;
  }
}

// ---------------- K5: out = gelu(v) @ Wproj^T ----------------
__global__ __launch_bounds__(256) void k_proj(
    const float* __restrict__ g, const float* __restrict__ Wp,
    float* __restrict__ out) {
  __shared__ float g_s[16][68];
  __shared__ float w_s[16][68];
  int rt = blockIdx.y * 64;
  int it = blockIdx.x * 64;
  int tid = threadIdx.x;
  int tx = tid & 15, ty = tid >> 4;
  int r4 = tid >> 2, cq = tid & 3;
  float acc[4][4] = {};
  for (int kc = 0; kc < 256; kc += 16) {
    float4 gv = *(const float4*)&g[(size_t)(rt + r4) * 256 + kc + cq * 4];
    g_s[cq*4+0][r4] = gv.x; g_s[cq*4+1][r4] = gv.y;
    g_s[cq*4+2][r4] = gv.z; g_s[cq*4+3][r4] = gv.w;
    float4 wv = *(const float4*)&Wp[(size_t)(it + r4) * 256 + kc + cq * 4];
    w_s[cq*4+0][r4] = wv.x; w_s[cq*4+1][r4] = wv.y;
    w_s[cq*4+2][r4] = wv.z; w_s[cq*4+3][r4] = wv.w;
    __syncthreads();
#pragma unroll
    for (int k = 0; k < 16; ++k) {
      float4 a = *(const float4*)&g_s[k][ty * 4];
      float4 bb = *(const float4*)&w_s[k][tx * 4];
      acc[0][0] = fmaf(a.x, bb.x, acc[0][0]); acc[0][1] = fmaf(a.x, bb.y, acc[0][1]);
      acc[0][2] = fmaf(a.x, bb.z, acc[0][2]); acc[0][3] = fmaf(a.x, bb.w, acc[0][3]);
      acc[1][0] = fmaf(a.y, bb.x, acc[1][0]); acc[1][1] = fmaf(a.y, bb.y, acc[1][1]);
      acc[1][2] = fmaf(a.y, bb.z, acc[1][2]); acc[1][3] = fmaf(a.y, bb.w, acc[1][3]);
      acc[2][0] = fmaf(a.z, bb.x, acc[2][0]); acc[2][1] = fmaf(a.z, bb.y, acc[2][1]);
      acc[2][2] = fmaf(a.z, bb.z, acc[2][2]); acc[2][3] = fmaf(a.z, bb.w, acc[2][3]);
      acc[3][0] = fmaf(a.w, bb.x, acc[3][0]); acc[3][1] = fmaf(a.w, bb.y, acc[3][1]);
      acc[3][2] = fmaf(a.w, bb.z, acc[3][2]); acc[3][3] = fmaf(a.w, bb.w, acc[3][3]);
    }
    __syncthreads();
  }
#pragma unroll
  for (int i = 0; i < 4; ++i) {
    float4 o = make_float4(acc[i][0], acc[i][1], acc[i][2], acc[i][3]);
    *(float4*)&out[(size_t)(rt + ty * 4 + i) * 256 + it + tx * 4] = o;
  }
}

extern "C" void kernel_launch(void* const* d_in, const int* in_sizes, int n_in,
                              void* d_out, int out_size, void* d_ws, size_t ws_size,
                              hipStream_t stream) {
  const float* x   = (const float*)d_in[0];
  const int*   adj = (const int*)d_in[1];
  // d_in[2] = label (unused)
  const float* Wq  = (const float*)d_in[3];
  const float* Wk  = (const float*)d_in[4];
  const float* Wv  = (const float*)d_in[5];
  const float* Lam = (const float*)d_in[6];
  const float* Wp  = (const float*)d_in[7];

  float* out  = (float*)d_out;                       // [8,1024,256]
  float* attn = out + (size_t)BB * TT * 256;         // [8,8,1024,1024]

  float* ws   = (float*)d_ws;
  float* xqk  = ws;                   // 8*1024*512
  float* xv   = ws + 4194304;         // 8*1024*256
  float* qsb  = ws + 6291456;         // 8*1024*256
  float* ksb  = ws + 8388608;         // 8*1024*256
  float* g    = ws + 10485760;        // 8*1024*256
  float* mrow = ws + 12582912;        // 8*8*1024
  float* rrow = ws + 12648448;        // 8*8*1024

  k_xw<<<BB * TT, 256, 0, stream>>>(x, Wq, Wk, Wv, xqk, xv);
  k_gcn<<<dim3(4, 8, BB), 256, 0, stream>>>(adj, xqk, qsb, ksb);
  k_score<<<BB * 32, 256, 0, stream>>>(qsb, ksb, adj, Lam, attn, mrow, rrow);
  k_pv<<<dim3(4, 8, BB), 256, 0, stream>>>(attn, xv, mrow, rrow, g);
  k_proj<<<dim3(4, 128), 256, 0, stream>>>(g, Wp, out);
}

// Round 2
// 515.889 us; speedup vs baseline: 1.6314x; 1.6314x over previous
//
#include <hip/hip_runtime.h>
#include <cmath>

#define TT 1024
#define BB 8

typedef __attribute__((ext_vector_type(4))) float f4;
typedef __attribute__((ext_vector_type(4))) unsigned int u4;
typedef __attribute__((ext_vector_type(8))) short s8v;

__device__ __forceinline__ ushort f2bf(float x) {
  unsigned u = __builtin_bit_cast(unsigned, x);
  unsigned r = (u + 0x7FFFu + ((u >> 16) & 1u)) >> 16;
  return (ushort)r;
}
__device__ __forceinline__ float bf2f(ushort b) {
  unsigned u = ((unsigned)b) << 16;
  return __builtin_bit_cast(float, u);
}
__device__ __forceinline__ void st8(ushort* p, const ushort* v) {
  u4 w;
  w.x = (unsigned)v[0] | ((unsigned)v[1] << 16);
  w.y = (unsigned)v[2] | ((unsigned)v[3] << 16);
  w.z = (unsigned)v[4] | ((unsigned)v[5] << 16);
  w.w = (unsigned)v[6] | ((unsigned)v[7] << 16);
  *(u4*)p = w;
}

// ---------------- K1: x @ {Wq/16, Wk, Wv} -> transposed bf16 hi/lo + vT ----------------
// grid 256: b=bid&7, t-tile 32. 256 threads: thread owns output column c (q,k,v).
__global__ __launch_bounds__(256, 1) void k_xw(
    const float* __restrict__ x, const float* __restrict__ Wq,
    const float* __restrict__ Wk, const float* __restrict__ Wv,
    ushort* __restrict__ xTqhi, ushort* __restrict__ xTqlo,
    ushort* __restrict__ xTkhi, ushort* __restrict__ xTklo,
    ushort* __restrict__ vT) {
  __shared__ float xs[32][256];
  int bid = blockIdx.x;
  int b = bid & 7, t0 = (bid >> 3) * 32;
  int tid = threadIdx.x;
#pragma unroll
  for (int i = 0; i < 8; ++i) {
    int e = i * 256 + tid;
    int t = e >> 6, c4 = (e & 63) * 4;
    *(f4*)&xs[t][c4] = *(const f4*)&x[((size_t)(b * 1024 + t0 + t)) * 256 + c4];
  }
  int c = tid, h = c >> 5, d = c & 31;
  float wqr[32], wkr[32], wvr[32];
#pragma unroll
  for (int e = 0; e < 32; ++e) {
    wqr[e] = Wq[e * 32 + d] * 0.0625f;  // fold scale = dim^-0.5 = 1/16 into Wq
    wkr[e] = Wk[e * 32 + d];
    wvr[e] = Wv[e * 32 + d];
  }
  __syncthreads();
  size_t rowq = ((size_t)(b * 256 + c)) * 1024 + t0;
#pragma unroll
  for (int tg = 0; tg < 4; ++tg) {
    ushort qh[8], ql[8], kh[8], kl[8], vh[8];
#pragma unroll
    for (int tt = 0; tt < 8; ++tt) {
      int t = tg * 8 + tt;
      float aq = 0.f, ak = 0.f, av = 0.f;
#pragma unroll
      for (int e = 0; e < 32; ++e) {
        float xe = xs[t][h * 32 + e];
        aq = fmaf(xe, wqr[e], aq);
        ak = fmaf(xe, wkr[e], ak);
        av = fmaf(xe, wvr[e], av);
      }
      ushort hq = f2bf(aq); qh[tt] = hq; ql[tt] = f2bf(aq - bf2f(hq));
      ushort hk = f2bf(ak); kh[tt] = hk; kl[tt] = f2bf(ak - bf2f(hk));
      vh[tt] = f2bf(av);
    }
    st8(xTqhi + rowq + tg * 8, qh);
    st8(xTqlo + rowq + tg * 8, ql);
    st8(xTkhi + rowq + tg * 8, kh);
    st8(xTklo + rowq + tg * 8, kl);
    st8(vT    + rowq + tg * 8, vh);
  }
}

// ---------------- K2: GCN q|k = adj @ xw via MFMA (A exact in bf16, X split hi/lo) ------
// grid 256: b=bid&7, r=bid>>3: lt=(r&15)*64, nt=r>>4 (0:q, 1:k). 4 waves: 32l x 128c each.
__global__ __launch_bounds__(256, 1) void k_gcn(
    const int* __restrict__ adj,
    const ushort* __restrict__ xTqhi, const ushort* __restrict__ xTqlo,
    const ushort* __restrict__ xTkhi, const ushort* __restrict__ xTklo,
    ushort* __restrict__ qhi, ushort* __restrict__ qlo,
    ushort* __restrict__ khi, ushort* __restrict__ klo) {
  int bid = blockIdx.x;
  int b = bid & 7, r = bid >> 3;
  int lt = (r & 15) * 64, nt = r >> 4;
  const ushort* XH = (nt ? xTkhi : xTqhi) + (size_t)b * 256 * 1024;
  const ushort* XL = (nt ? xTklo : xTqlo) + (size_t)b * 256 * 1024;
  ushort* OH = (nt ? khi : qhi) + (size_t)b * 1024 * 256;
  ushort* OL = (nt ? klo : qlo) + (size_t)b * 1024 * 256;
  const int* AD = adj + (size_t)b * 1024 * 1024;
  int tid = threadIdx.x, wid = tid >> 6, lane = tid & 63;
  int lrow = lane & 15, lk = lane >> 4;
  int wr = wid >> 1, wc = wid & 1;
  int rbase = lt + wr * 32;
  int cbase = wc * 128;
  f4 acc[2][8];
#pragma unroll
  for (int i = 0; i < 2; ++i)
#pragma unroll
    for (int j = 0; j < 8; ++j) acc[i][j] = (f4)(0.f);

  for (int k0 = 0; k0 < 1024; k0 += 32) {
    s8v afr[2];
#pragma unroll
    for (int rq = 0; rq < 2; ++rq) {
      const int* ap = &AD[(size_t)(rbase + rq * 16 + lrow) * 1024 + k0 + lk * 8];
      int4 a0 = *(const int4*)ap;
      int4 a1 = *(const int4*)(ap + 4);
      u4 fw;
      fw.x = (a0.x ? 0x3F80u : 0u) | (a0.y ? 0x3F800000u : 0u);
      fw.y = (a0.z ? 0x3F80u : 0u) | (a0.w ? 0x3F800000u : 0u);
      fw.z = (a1.x ? 0x3F80u : 0u) | (a1.y ? 0x3F800000u : 0u);
      fw.w = (a1.z ? 0x3F80u : 0u) | (a1.w ? 0x3F800000u : 0u);
      afr[rq] = __builtin_bit_cast(s8v, fw);
    }
#pragma unroll
    for (int nq = 0; nq < 8; ++nq) {
      int col = cbase + nq * 16 + lrow;
      s8v bh = *(const s8v*)&XH[(size_t)col * 1024 + k0 + lk * 8];
      s8v bl = *(const s8v*)&XL[(size_t)col * 1024 + k0 + lk * 8];
#pragma unroll
      for (int rq = 0; rq < 2; ++rq) {
        acc[rq][nq] = __builtin_amdgcn_mfma_f32_16x16x32_bf16(afr[rq], bh, acc[rq][nq], 0, 0, 0);
        acc[rq][nq] = __builtin_amdgcn_mfma_f32_16x16x32_bf16(afr[rq], bl, acc[rq][nq], 0, 0, 0);
      }
    }
  }
#pragma unroll
  for (int rq = 0; rq < 2; ++rq)
#pragma unroll
    for (int nq = 0; nq < 8; ++nq)
#pragma unroll
      for (int e = 0; e < 4; ++e) {
        float v = acc[rq][nq][e];
        int row = rbase + rq * 16 + lk * 4 + e;
        int col = cbase + nq * 16 + lrow;
        ushort hi = f2bf(v);
        ushort lo = f2bf(v - bf2f(hi));
        OH[(size_t)row * 256 + col] = hi;
        OL[(size_t)row * 256 + col] = lo;
      }
}

// ---------------- K3: scores via split-bf16 MFMA + in-register Lam mix + softmax --------
// grid 256: b=bid&7, lt=(bid>>3)*32. 4 waves: (wr: 16-row half) x (wc: t-interleave).
// Pass1: online (m,sum) stats only. Pass2: recompute, write final softmax to attn.
__global__ __launch_bounds__(256, 1) void k_score(
    const ushort* __restrict__ qhi, const ushort* __restrict__ qlo,
    const ushort* __restrict__ khi, const ushort* __restrict__ klo,
    const int* __restrict__ adj, const float* __restrict__ Lam,
    float* __restrict__ attn) {
  __shared__ float sm_m[2][32][8];
  __shared__ float sm_s[2][32][8];
  __shared__ float fin_m[32][8];
  __shared__ float fin_r[32][8];
  int bid = blockIdx.x;
  int b = bid & 7, lt = (bid >> 3) * 32;
  int tid = threadIdx.x, wid = tid >> 6, lane = tid & 63;
  int lrow = lane & 15, lk = lane >> 4;
  int wr = wid >> 1, wc = wid & 1;
  const ushort* QH = qhi + (size_t)b * 1024 * 256;
  const ushort* QL = qlo + (size_t)b * 1024 * 256;
  const ushort* KH = khi + (size_t)b * 1024 * 256;
  const ushort* KL = klo + (size_t)b * 1024 * 256;
  const int* AD = adj + (size_t)b * 1024 * 1024;
  float* AT = attn + (size_t)b * 8 * 1024 * 1024;

  s8v qfh[8], qfl[8];
  int qrow = lt + wr * 16 + lrow;
#pragma unroll
  for (int h = 0; h < 8; ++h) {
    qfh[h] = *(const s8v*)&QH[(size_t)qrow * 256 + h * 32 + lk * 8];
    qfl[h] = *(const s8v*)&QL[(size_t)qrow * 256 + h * 32 + lk * 8];
  }
  float ms[4][8], ss[4][8];
#pragma unroll
  for (int e = 0; e < 4; ++e)
#pragma unroll
    for (int i2 = 0; i2 < 8; ++i2) { ms[e][i2] = -3.0e38f; ss[e][i2] = 0.f; }

  // ---- pass 1: stats ----
  for (int it = 0; it < 32; ++it) {
    int t0 = (it * 2 + wc) * 16;
    f4 acc[8];
#pragma unroll
    for (int h = 0; h < 8; ++h) {
      s8v kh = *(const s8v*)&KH[(size_t)(t0 + lrow) * 256 + h * 32 + lk * 8];
      s8v kl = *(const s8v*)&KL[(size_t)(t0 + lrow) * 256 + h * 32 + lk * 8];
      f4 a = (f4)(0.f);
      a = __builtin_amdgcn_mfma_f32_16x16x32_bf16(qfh[h], kh, a, 0, 0, 0);
      a = __builtin_amdgcn_mfma_f32_16x16x32_bf16(qfh[h], kl, a, 0, 0, 0);
      a = __builtin_amdgcn_mfma_f32_16x16x32_bf16(qfl[h], kh, a, 0, 0, 0);
      acc[h] = a;
    }
#pragma unroll
    for (int e = 0; e < 4; ++e) {
      int row = lt + wr * 16 + lk * 4 + e;
      int a = AD[(size_t)row * 1024 + t0 + lrow];
      bool pred = a > 0;
      float raw[8];
#pragma unroll
      for (int h = 0; h < 8; ++h) { float v = acc[h][e]; raw[h] = fmaxf(v, 0.01f * v); }
#pragma unroll
      for (int i2 = 0; i2 < 8; ++i2) {
        float s = 0.f;
#pragma unroll
        for (int j = 0; j < 8; ++j) s = fmaf(Lam[i2 * 8 + j], raw[j], s);
        float d = s - ms[e][i2];
        float ex = __expf(fminf(d, -d));
        float snew = (d > 0.f) ? fmaf(ss[e][i2], ex, 1.f) : (ss[e][i2] + ex);
        float mnew = fmaxf(ms[e][i2], s);
        if (pred) { ss[e][i2] = snew; ms[e][i2] = mnew; }
      }
    }
  }
  // reduce over the 16 col-lanes
#pragma unroll
  for (int e = 0; e < 4; ++e)
#pragma unroll
    for (int i2 = 0; i2 < 8; ++i2) {
      float mm = ms[e][i2], sv = ss[e][i2];
      for (int off = 1; off < 16; off <<= 1) {
        float om = __shfl_xor(mm, off, 64);
        float os = __shfl_xor(sv, off, 64);
        float d = mm - om;
        float ex = __expf(fminf(d, -d));
        float sA = fmaf(os, ex, sv);
        float sB = fmaf(sv, ex, os);
        sv = (d >= 0.f) ? sA : sB;
        mm = fmaxf(mm, om);
      }
      ms[e][i2] = mm; ss[e][i2] = sv;
    }
  if (lrow == 0) {
#pragma unroll
    for (int e = 0; e < 4; ++e)
#pragma unroll
      for (int i2 = 0; i2 < 8; ++i2) {
        sm_m[wc][wr * 16 + lk * 4 + e][i2] = ms[e][i2];
        sm_s[wc][wr * 16 + lk * 4 + e][i2] = ss[e][i2];
      }
  }
  __syncthreads();
  {
    int rw = tid >> 3, i2 = tid & 7;
    float m0 = sm_m[0][rw][i2], m1 = sm_m[1][rw][i2];
    float s0 = sm_s[0][rw][i2], s1 = sm_s[1][rw][i2];
    float M = fmaxf(m0, m1);
    float S = s0 * __expf(m0 - M) + s1 * __expf(m1 - M);
    fin_m[rw][i2] = M;
    fin_r[rw][i2] = 1.f / S;
  }
  __syncthreads();
#pragma unroll
  for (int e = 0; e < 4; ++e)
#pragma unroll
    for (int i2 = 0; i2 < 8; ++i2) {
      ms[e][i2] = fin_m[wr * 16 + lk * 4 + e][i2];
      ss[e][i2] = fin_r[wr * 16 + lk * 4 + e][i2];
    }
  // ---- pass 2: recompute + write final softmax ----
  for (int it = 0; it < 32; ++it) {
    int t0 = (it * 2 + wc) * 16;
    f4 acc[8];
#pragma unroll
    for (int h = 0; h < 8; ++h) {
      s8v kh = *(const s8v*)&KH[(size_t)(t0 + lrow) * 256 + h * 32 + lk * 8];
      s8v kl = *(const s8v*)&KL[(size_t)(t0 + lrow) * 256 + h * 32 + lk * 8];
      f4 a = (f4)(0.f);
      a = __builtin_amdgcn_mfma_f32_16x16x32_bf16(qfh[h], kh, a, 0, 0, 0);
      a = __builtin_amdgcn_mfma_f32_16x16x32_bf16(qfh[h], kl, a, 0, 0, 0);
      a = __builtin_amdgcn_mfma_f32_16x16x32_bf16(qfl[h], kh, a, 0, 0, 0);
      acc[h] = a;
    }
#pragma unroll
    for (int e = 0; e < 4; ++e) {
      int row = lt + wr * 16 + lk * 4 + e;
      int a = AD[(size_t)row * 1024 + t0 + lrow];
      bool pred = a > 0;
      float raw[8];
#pragma unroll
      for (int h = 0; h < 8; ++h) { float v = acc[h][e]; raw[h] = fmaxf(v, 0.01f * v); }
#pragma unroll
      for (int i2 = 0; i2 < 8; ++i2) {
        float s = 0.f;
#pragma unroll
        for (int j = 0; j < 8; ++j) s = fmaf(Lam[i2 * 8 + j], raw[j], s);
        float p = pred ? __expf(s - ms[e][i2]) * ss[e][i2] : 0.f;
        AT[((size_t)i2 * 1024 + row) * 1024 + t0 + lrow] = p;
      }
    }
  }
}

// ---------------- K4: PV via bf16 MFMA + GELU -> g ----------------
// grid 1024: b=bid&7, h=(bid>>3)&7, lt=(bid>>6)*64. 4 waves: 16 rows each.
__global__ __launch_bounds__(256, 4) void k_pv(
    const float* __restrict__ attn, const ushort* __restrict__ vT,
    float* __restrict__ g) {
  __shared__ ushort Vs[32][136];           // [d][t], stride 136 elems (2-way banks)
  __shared__ unsigned pt[64 * 128 / 2];    // P tile [64][128] bf16, XOR-swizzled
  int bid = blockIdx.x;
  int b = bid & 7, h = (bid >> 3) & 7, lt = (bid >> 6) * 64;
  int tid = threadIdx.x, wid = tid >> 6, lane = tid & 63;
  int lrow = lane & 15, lk = lane >> 4;
  const float* AT = attn + ((size_t)(b * 8 + h) * 1024 + lt) * 1024;
  const ushort* VTb = vT + (size_t)(b * 256 + h * 32) * 1024;
  char* ptb = (char*)pt;
  f4 acc[2];
  acc[0] = (f4)(0.f); acc[1] = (f4)(0.f);

  for (int tc = 0; tc < 1024; tc += 128) {
    {  // stage V chunk [32][128]
      int col = tid >> 3, toff = (tid & 7) * 16;
      u4 v0 = *(const u4*)&VTb[(size_t)col * 1024 + tc + toff];
      u4 v1 = *(const u4*)&VTb[(size_t)col * 1024 + tc + toff + 8];
      *(u4*)&Vs[col][toff] = v0;
      *(u4*)&Vs[col][toff + 8] = v1;
    }
    {  // stage P chunk [64][128] -> bf16 swizzled
      int row = tid >> 2, tq = (tid & 3) * 32;
      const float* src = &AT[(size_t)row * 1024 + tc + tq];
#pragma unroll
      for (int i = 0; i < 4; ++i) {
        f4 p0 = *(const f4*)&src[i * 8];
        f4 p1 = *(const f4*)&src[i * 8 + 4];
        u4 pk;
        pk.x = (unsigned)f2bf(p0[0]) | ((unsigned)f2bf(p0[1]) << 16);
        pk.y = (unsigned)f2bf(p0[2]) | ((unsigned)f2bf(p0[3]) << 16);
        pk.z = (unsigned)f2bf(p1[0]) | ((unsigned)f2bf(p1[1]) << 16);
        pk.w = (unsigned)f2bf(p1[2]) | ((unsigned)f2bf(p1[3]) << 16);
        int t = tq + i * 8;
        int boff = row * 256 + ((t * 2) ^ ((row & 7) << 4));
        *(u4*)(ptb + boff) = pk;
      }
    }
    __syncthreads();
    int prow = wid * 16 + lrow;
#pragma unroll
    for (int ks = 0; ks < 4; ++ks) {
      int t = ks * 32 + lk * 8;
      int aoff = prow * 256 + ((t * 2) ^ ((prow & 7) << 4));
      s8v af = *(const s8v*)(ptb + aoff);
#pragma unroll
      for (int nq = 0; nq < 2; ++nq) {
        s8v bf = *(const s8v*)&Vs[nq * 16 + lrow][t];
        acc[nq] = __builtin_amdgcn_mfma_f32_16x16x32_bf16(af, bf, acc[nq], 0, 0, 0);
      }
    }
    __syncthreads();
  }
#pragma unroll
  for (int nq = 0; nq < 2; ++nq)
#pragma unroll
    for (int e = 0; e < 4; ++e) {
      float v = acc[nq][e];
      float ge = 0.5f * v * (1.f + erff(v * 0.70710678118654752f));
      int row = lt + wid * 16 + lk * 4 + e;
      int col = h * 32 + nq * 16 + lrow;
      g[(size_t)(b * 1024 + row) * 256 + col] = ge;
    }
}

// ---------------- K5: out = gelu(v) @ Wproj^T (fp32, small) ----------------
__global__ __launch_bounds__(256) void k_proj(
    const float* __restrict__ g, const float* __restrict__ Wp,
    float* __restrict__ out) {
  __shared__ float g_s[16][68];
  __shared__ float w_s[16][68];
  int rt = blockIdx.y * 64;
  int it = blockIdx.x * 64;
  int tid = threadIdx.x;
  int tx = tid & 15, ty = tid >> 4;
  int r4 = tid >> 2, cq = tid & 3;
  float acc[4][4] = {};
  for (int kc = 0; kc < 256; kc += 16) {
    float4 gv = *(const float4*)&g[(size_t)(rt + r4) * 256 + kc + cq * 4];
    g_s[cq * 4 + 0][r4] = gv.x; g_s[cq * 4 + 1][r4] = gv.y;
    g_s[cq * 4 + 2][r4] = gv.z; g_s[cq * 4 + 3][r4] = gv.w;
    float4 wv = *(const float4*)&Wp[(size_t)(it + r4) * 256 + kc + cq * 4];
    w_s[cq * 4 + 0][r4] = wv.x; w_s[cq * 4 + 1][r4] = wv.y;
    w_s[cq * 4 + 2][r4] = wv.z; w_s[cq * 4 + 3][r4] = wv.w;
    __syncthreads();
#pragma unroll
    for (int k = 0; k < 16; ++k) {
      float4 a = *(const float4*)&g_s[k][ty * 4];
      float4 bb = *(const float4*)&w_s[k][tx * 4];
      acc[0][0] = fmaf(a.x, bb.x, acc[0][0]); acc[0][1] = fmaf(a.x, bb.y, acc[0][1]);
      acc[0][2] = fmaf(a.x, bb.z, acc[0][2]); acc[0][3] = fmaf(a.x, bb.w, acc[0][3]);
      acc[1][0] = fmaf(a.y, bb.x, acc[1][0]); acc[1][1] = fmaf(a.y, bb.y, acc[1][1]);
      acc[1][2] = fmaf(a.y, bb.z, acc[1][2]); acc[1][3] = fmaf(a.y, bb.w, acc[1][3]);
      acc[2][0] = fmaf(a.z, bb.x, acc[2][0]); acc[2][1] = fmaf(a.z, bb.y, acc[2][1]);
      acc[2][2] = fmaf(a.z, bb.z, acc[2][2]); acc[2][3] = fmaf(a.z, bb.w, acc[2][3]);
      acc[3][0] = fmaf(a.w, bb.x, acc[3][0]); acc[3][1] = fmaf(a.w, bb.y, acc[3][1]);
      acc[3][2] = fmaf(a.w, bb.z, acc[3][2]); acc[3][3] = fmaf(a.w, bb.w, acc[3][3]);
    }
    __syncthreads();
  }
#pragma unroll
  for (int i = 0; i < 4; ++i) {
    float4 o = make_float4(acc[i][0], acc[i][1], acc[i][2], acc[i][3]);
    *(float4*)&out[(size_t)(rt + ty * 4 + i) * 256 + it + tx * 4] = o;
  }
}

extern "C" void kernel_launch(void* const* d_in, const int* in_sizes, int n_in,
                              void* d_out, int out_size, void* d_ws, size_t ws_size,
                              hipStream_t stream) {
  const float* x   = (const float*)d_in[0];
  const int*   adj = (const int*)d_in[1];
  const float* Wq  = (const float*)d_in[3];
  const float* Wk  = (const float*)d_in[4];
  const float* Wv  = (const float*)d_in[5];
  const float* Lam = (const float*)d_in[6];
  const float* Wp  = (const float*)d_in[7];

  float* out  = (float*)d_out;                 // [8,1024,256]
  float* attn = out + (size_t)BB * TT * 256;   // [8,8,1024,1024]

  const size_t SZ = (size_t)8 * 1024 * 256;    // 2097152 elements
  char* base = (char*)d_ws;
  ushort* xTqhi = (ushort*)(base + 0 * SZ * 2);
  ushort* xTqlo = (ushort*)(base + 1 * SZ * 2);
  ushort* xTkhi = (ushort*)(base + 2 * SZ * 2);
  ushort* xTklo = (ushort*)(base + 3 * SZ * 2);
  ushort* vT    = (ushort*)(base + 4 * SZ * 2);
  ushort* qhi   = (ushort*)(base + 5 * SZ * 2);
  ushort* qlo   = (ushort*)(base + 6 * SZ * 2);
  ushort* khi   = (ushort*)(base + 7 * SZ * 2);
  ushort* klo   = (ushort*)(base + 8 * SZ * 2);
  float*  gbuf  = (float*)(base + 9 * SZ * 2); // SZ floats

  k_xw<<<256, 256, 0, stream>>>(x, Wq, Wk, Wv, xTqhi, xTqlo, xTkhi, xTklo, vT);
  k_gcn<<<256, 256, 0, stream>>>(adj, xTqhi, xTqlo, xTkhi, xTklo, qhi, qlo, khi, klo);
  k_score<<<256, 256, 0, stream>>>(qhi, qlo, khi, klo, adj, Lam, attn);
  k_pv<<<1024, 256, 0, stream>>>(attn, vT, gbuf);
  k_proj<<<dim3(4, 128), 256, 0, stream>>>(gbuf, Wp, out);
}

// Round 3
// 515.038 us; speedup vs baseline: 1.6341x; 1.0017x over previous
//
#include <hip/hip_runtime.h>
#include <cmath>

#define TT 1024
#define BB 8

typedef __attribute__((ext_vector_type(4))) float f4;
typedef __attribute__((ext_vector_type(4))) unsigned int u4;
typedef __attribute__((ext_vector_type(8))) short s8v;

__device__ __forceinline__ ushort f2bf(float x) {
  unsigned u = __builtin_bit_cast(unsigned, x);
  unsigned r = (u + 0x7FFFu + ((u >> 16) & 1u)) >> 16;
  return (ushort)r;
}
__device__ __forceinline__ float bf2f(ushort b) {
  unsigned u = ((unsigned)b) << 16;
  return __builtin_bit_cast(float, u);
}
__device__ __forceinline__ void st8(ushort* p, const ushort* v) {
  u4 w;
  w.x = (unsigned)v[0] | ((unsigned)v[1] << 16);
  w.y = (unsigned)v[2] | ((unsigned)v[3] << 16);
  w.z = (unsigned)v[4] | ((unsigned)v[5] << 16);
  w.w = (unsigned)v[6] | ((unsigned)v[7] << 16);
  *(u4*)p = w;
}

// ---------------- K1: x @ {Wq/16, Wk, Wv} -> transposed bf16 hi/lo + vT ----------------
__global__ __launch_bounds__(256, 1) void k_xw(
    const float* __restrict__ x, const float* __restrict__ Wq,
    const float* __restrict__ Wk, const float* __restrict__ Wv,
    ushort* __restrict__ xTqhi, ushort* __restrict__ xTqlo,
    ushort* __restrict__ xTkhi, ushort* __restrict__ xTklo,
    ushort* __restrict__ vT) {
  __shared__ float xs[32][256];
  int bid = blockIdx.x;
  int b = bid & 7, t0 = (bid >> 3) * 32;
  int tid = threadIdx.x;
#pragma unroll
  for (int i = 0; i < 8; ++i) {
    int e = i * 256 + tid;
    int t = e >> 6, c4 = (e & 63) * 4;
    *(f4*)&xs[t][c4] = *(const f4*)&x[((size_t)(b * 1024 + t0 + t)) * 256 + c4];
  }
  int c = tid, h = c >> 5, d = c & 31;
  float wqr[32], wkr[32], wvr[32];
#pragma unroll
  for (int e = 0; e < 32; ++e) {
    wqr[e] = Wq[e * 32 + d] * 0.0625f;  // fold scale = dim^-0.5 = 1/16 into Wq
    wkr[e] = Wk[e * 32 + d];
    wvr[e] = Wv[e * 32 + d];
  }
  __syncthreads();
  size_t rowq = ((size_t)(b * 256 + c)) * 1024 + t0;
#pragma unroll
  for (int tg = 0; tg < 4; ++tg) {
    ushort qh[8], ql[8], kh[8], kl[8], vh[8];
#pragma unroll
    for (int tt = 0; tt < 8; ++tt) {
      int t = tg * 8 + tt;
      float aq = 0.f, ak = 0.f, av = 0.f;
#pragma unroll
      for (int e = 0; e < 32; ++e) {
        float xe = xs[t][h * 32 + e];
        aq = fmaf(xe, wqr[e], aq);
        ak = fmaf(xe, wkr[e], ak);
        av = fmaf(xe, wvr[e], av);
      }
      ushort hq = f2bf(aq); qh[tt] = hq; ql[tt] = f2bf(aq - bf2f(hq));
      ushort hk = f2bf(ak); kh[tt] = hk; kl[tt] = f2bf(ak - bf2f(hk));
      vh[tt] = f2bf(av);
    }
    st8(xTqhi + rowq + tg * 8, qh);
    st8(xTqlo + rowq + tg * 8, ql);
    st8(xTkhi + rowq + tg * 8, kh);
    st8(xTklo + rowq + tg * 8, kl);
    st8(vT    + rowq + tg * 8, vh);
  }
}

// ---------------- K2: GCN [q|k] = adj @ [xq|xk] via MFMA, grid 512 ----------------
// bid: ct(4: 2 q-halves, 2 k-halves), lt(16: 64 rows), b(8). 4 waves: 32l x 64c.
__global__ __launch_bounds__(256, 1) void k_gcn(
    const int* __restrict__ adj,
    const ushort* __restrict__ xTqhi, const ushort* __restrict__ xTqlo,
    const ushort* __restrict__ xTkhi, const ushort* __restrict__ xTklo,
    ushort* __restrict__ qhi, ushort* __restrict__ qlo,
    ushort* __restrict__ khi, ushort* __restrict__ klo) {
  int bid = blockIdx.x;
  int ct = bid & 3, lt = ((bid >> 2) & 15) * 64, b = bid >> 6;
  int nt = ct >> 1, cbase = (ct & 1) * 128;
  const ushort* XH = (nt ? xTkhi : xTqhi) + (size_t)b * 256 * 1024;
  const ushort* XL = (nt ? xTklo : xTqlo) + (size_t)b * 256 * 1024;
  ushort* OH = (nt ? khi : qhi) + (size_t)b * 1024 * 256;
  ushort* OL = (nt ? klo : qlo) + (size_t)b * 1024 * 256;
  const int* AD = adj + (size_t)b * 1024 * 1024;
  int tid = threadIdx.x, wid = tid >> 6, lane = tid & 63;
  int lrow = lane & 15, lk = lane >> 4;
  int wr = wid >> 1, wc = wid & 1;
  int rbase = lt + wr * 32;
  int cb2 = cbase + wc * 64;
  f4 acc[2][4];
#pragma unroll
  for (int i = 0; i < 2; ++i)
#pragma unroll
    for (int j = 0; j < 4; ++j) acc[i][j] = (f4)(0.f);

  for (int k0 = 0; k0 < 1024; k0 += 32) {
    s8v afr[2];
#pragma unroll
    for (int rq = 0; rq < 2; ++rq) {
      const int* ap = &AD[(size_t)(rbase + rq * 16 + lrow) * 1024 + k0 + lk * 8];
      int4 a0 = *(const int4*)ap;
      int4 a1 = *(const int4*)(ap + 4);
      u4 fw;
      fw.x = (a0.x ? 0x3F80u : 0u) | (a0.y ? 0x3F800000u : 0u);
      fw.y = (a0.z ? 0x3F80u : 0u) | (a0.w ? 0x3F800000u : 0u);
      fw.z = (a1.x ? 0x3F80u : 0u) | (a1.y ? 0x3F800000u : 0u);
      fw.w = (a1.z ? 0x3F80u : 0u) | (a1.w ? 0x3F800000u : 0u);
      afr[rq] = __builtin_bit_cast(s8v, fw);
    }
#pragma unroll
    for (int nq = 0; nq < 4; ++nq) {
      int col = cb2 + nq * 16 + lrow;
      s8v bh = *(const s8v*)&XH[(size_t)col * 1024 + k0 + lk * 8];
      s8v bl = *(const s8v*)&XL[(size_t)col * 1024 + k0 + lk * 8];
#pragma unroll
      for (int rq = 0; rq < 2; ++rq) {
        acc[rq][nq] = __builtin_amdgcn_mfma_f32_16x16x32_bf16(afr[rq], bh, acc[rq][nq], 0, 0, 0);
        acc[rq][nq] = __builtin_amdgcn_mfma_f32_16x16x32_bf16(afr[rq], bl, acc[rq][nq], 0, 0, 0);
      }
    }
  }
#pragma unroll
  for (int rq = 0; rq < 2; ++rq)
#pragma unroll
    for (int nq = 0; nq < 4; ++nq)
#pragma unroll
      for (int e = 0; e < 4; ++e) {
        float v = acc[rq][nq][e];
        int row = rbase + rq * 16 + lk * 4 + e;
        int col = cb2 + nq * 16 + lrow;
        ushort hi = f2bf(v);
        ushort lo = f2bf(v - bf2f(hi));
        OH[(size_t)row * 256 + col] = hi;
        OL[(size_t)row * 256 + col] = lo;
      }
}

// ---------------- K3a: score stats, grid 2048 (b x 32 row-tiles x 8 col-chunks) --------
__global__ __launch_bounds__(256, 1) void k_stats(
    const ushort* __restrict__ qhi, const ushort* __restrict__ qlo,
    const ushort* __restrict__ khi, const ushort* __restrict__ klo,
    const int* __restrict__ adj, const float* __restrict__ Lam,
    float* __restrict__ pm, float* __restrict__ ps) {
  __shared__ float sm_m[2][32][8];
  __shared__ float sm_s[2][32][8];
  int bid = blockIdx.x;
  int b = bid >> 8;
  int lt = ((bid >> 3) & 31) << 5;
  int tc = bid & 7;
  int tid = threadIdx.x, wid = tid >> 6, lane = tid & 63;
  int lrow = lane & 15, lk = lane >> 4;
  int wr = wid >> 1, wc = wid & 1;
  const ushort* QH = qhi + (size_t)b * 1024 * 256;
  const ushort* QL = qlo + (size_t)b * 1024 * 256;
  const ushort* KH = khi + (size_t)b * 1024 * 256;
  const ushort* KL = klo + (size_t)b * 1024 * 256;
  const int* AD = adj + (size_t)b * 1024 * 1024;

  s8v qfh[8], qfl[8];
  int qrow = lt + wr * 16 + lrow;
#pragma unroll
  for (int h = 0; h < 8; ++h) {
    qfh[h] = *(const s8v*)&QH[(size_t)qrow * 256 + h * 32 + lk * 8];
    qfl[h] = *(const s8v*)&QL[(size_t)qrow * 256 + h * 32 + lk * 8];
  }
  float ms[4][8], ss[4][8];
#pragma unroll
  for (int e = 0; e < 4; ++e)
#pragma unroll
    for (int i2 = 0; i2 < 8; ++i2) { ms[e][i2] = -3.0e38f; ss[e][i2] = 0.f; }

  for (int it = 0; it < 4; ++it) {
    int t0 = tc * 128 + (it * 2 + wc) * 16;
    f4 acc[8];
#pragma unroll
    for (int h = 0; h < 8; ++h) {
      s8v kh = *(const s8v*)&KH[(size_t)(t0 + lrow) * 256 + h * 32 + lk * 8];
      s8v kl = *(const s8v*)&KL[(size_t)(t0 + lrow) * 256 + h * 32 + lk * 8];
      f4 a = (f4)(0.f);
      a = __builtin_amdgcn_mfma_f32_16x16x32_bf16(qfh[h], kh, a, 0, 0, 0);
      a = __builtin_amdgcn_mfma_f32_16x16x32_bf16(qfh[h], kl, a, 0, 0, 0);
      a = __builtin_amdgcn_mfma_f32_16x16x32_bf16(qfl[h], kh, a, 0, 0, 0);
      acc[h] = a;
    }
#pragma unroll
    for (int e = 0; e < 4; ++e) {
      int row = lt + wr * 16 + lk * 4 + e;
      int a = AD[(size_t)row * 1024 + t0 + lrow];
      bool pred = a > 0;
      float raw[8];
#pragma unroll
      for (int h = 0; h < 8; ++h) { float v = acc[h][e]; raw[h] = fmaxf(v, 0.01f * v); }
#pragma unroll
      for (int i2 = 0; i2 < 8; ++i2) {
        float s = 0.f;
#pragma unroll
        for (int j = 0; j < 8; ++j) s = fmaf(Lam[i2 * 8 + j], raw[j], s);
        float d = s - ms[e][i2];
        float ex = __expf(fminf(d, -d));
        float snew = (d > 0.f) ? fmaf(ss[e][i2], ex, 1.f) : (ss[e][i2] + ex);
        float mnew = fmaxf(ms[e][i2], s);
        if (pred) { ss[e][i2] = snew; ms[e][i2] = mnew; }
      }
    }
  }
  // reduce across the 16 col-lanes (bits 0..3 of lane)
#pragma unroll
  for (int e = 0; e < 4; ++e)
#pragma unroll
    for (int i2 = 0; i2 < 8; ++i2) {
      float mm = ms[e][i2], sv = ss[e][i2];
      for (int off = 1; off < 16; off <<= 1) {
        float om = __shfl_xor(mm, off, 64);
        float os = __shfl_xor(sv, off, 64);
        float d = mm - om;
        float ex = __expf(fminf(d, -d));
        float sA = fmaf(os, ex, sv);
        float sB = fmaf(sv, ex, os);
        sv = (d >= 0.f) ? sA : sB;
        mm = fmaxf(mm, om);
      }
      ms[e][i2] = mm; ss[e][i2] = sv;
    }
  if (lrow == 0) {
#pragma unroll
    for (int e = 0; e < 4; ++e)
#pragma unroll
      for (int i2 = 0; i2 < 8; ++i2) {
        sm_m[wc][wr * 16 + lk * 4 + e][i2] = ms[e][i2];
        sm_s[wc][wr * 16 + lk * 4 + e][i2] = ss[e][i2];
      }
  }
  __syncthreads();
  {
    int rw = tid >> 3, i2 = tid & 7;
    float m0 = sm_m[0][rw][i2], m1 = sm_m[1][rw][i2];
    float s0 = sm_s[0][rw][i2], s1 = sm_s[1][rw][i2];
    float M = fmaxf(m0, m1);
    float S = s0 * __expf(m0 - M) + s1 * __expf(m1 - M);
    size_t R = ((size_t)(b * 8 + i2) * 1024 + lt + rw);
    pm[R * 8 + tc] = M;
    ps[R * 8 + tc] = S;
  }
}

// ---------------- K3b: reduce 8 chunk-partials -> (m, 1/sum) per row ----------------
__global__ __launch_bounds__(256) void k_reduce(
    const float* __restrict__ pm, const float* __restrict__ ps,
    float* __restrict__ fm, float* __restrict__ fr) {
  int R = blockIdx.x * 256 + threadIdx.x;   // 65536 rows
  f4 m0 = *(const f4*)&pm[(size_t)R * 8];
  f4 m1 = *(const f4*)&pm[(size_t)R * 8 + 4];
  f4 s0 = *(const f4*)&ps[(size_t)R * 8];
  f4 s1 = *(const f4*)&ps[(size_t)R * 8 + 4];
  float M = fmaxf(fmaxf(fmaxf(m0.x, m0.y), fmaxf(m0.z, m0.w)),
                  fmaxf(fmaxf(m1.x, m1.y), fmaxf(m1.z, m1.w)));
  float S = s0.x * __expf(m0.x - M) + s0.y * __expf(m0.y - M) +
            s0.z * __expf(m0.z - M) + s0.w * __expf(m0.w - M) +
            s1.x * __expf(m1.x - M) + s1.y * __expf(m1.y - M) +
            s1.z * __expf(m1.z - M) + s1.w * __expf(m1.w - M);
  fm[R] = M;
  fr[R] = 1.f / S;
}

// ---------------- K3c: recompute scores + write final softmax p, grid 2048 ----------
__global__ __launch_bounds__(256, 1) void k_final(
    const ushort* __restrict__ qhi, const ushort* __restrict__ qlo,
    const ushort* __restrict__ khi, const ushort* __restrict__ klo,
    const int* __restrict__ adj, const float* __restrict__ Lam,
    const float* __restrict__ fm, const float* __restrict__ fr,
    float* __restrict__ attn) {
  __shared__ float fin_m[32][8];
  __shared__ float fin_r[32][8];
  int bid = blockIdx.x;
  int b = bid >> 8;
  int lt = ((bid >> 3) & 31) << 5;
  int tc = bid & 7;
  int tid = threadIdx.x, wid = tid >> 6, lane = tid & 63;
  int lrow = lane & 15, lk = lane >> 4;
  int wr = wid >> 1, wc = wid & 1;
  const ushort* QH = qhi + (size_t)b * 1024 * 256;
  const ushort* QL = qlo + (size_t)b * 1024 * 256;
  const ushort* KH = khi + (size_t)b * 1024 * 256;
  const ushort* KL = klo + (size_t)b * 1024 * 256;
  const int* AD = adj + (size_t)b * 1024 * 1024;
  float* AT = attn + (size_t)b * 8 * 1024 * 1024;
  {
    int rw = tid >> 3, i2 = tid & 7;
    size_t R = ((size_t)(b * 8 + i2) * 1024 + lt + rw);
    fin_m[rw][i2] = fm[R];
    fin_r[rw][i2] = fr[R];
  }
  s8v qfh[8], qfl[8];
  int qrow = lt + wr * 16 + lrow;
#pragma unroll
  for (int h = 0; h < 8; ++h) {
    qfh[h] = *(const s8v*)&QH[(size_t)qrow * 256 + h * 32 + lk * 8];
    qfl[h] = *(const s8v*)&QL[(size_t)qrow * 256 + h * 32 + lk * 8];
  }
  __syncthreads();
  float ms[4][8], rs[4][8];
#pragma unroll
  for (int e = 0; e < 4; ++e)
#pragma unroll
    for (int i2 = 0; i2 < 8; ++i2) {
      ms[e][i2] = fin_m[wr * 16 + lk * 4 + e][i2];
      rs[e][i2] = fin_r[wr * 16 + lk * 4 + e][i2];
    }
  for (int it = 0; it < 4; ++it) {
    int t0 = tc * 128 + (it * 2 + wc) * 16;
    f4 acc[8];
#pragma unroll
    for (int h = 0; h < 8; ++h) {
      s8v kh = *(const s8v*)&KH[(size_t)(t0 + lrow) * 256 + h * 32 + lk * 8];
      s8v kl = *(const s8v*)&KL[(size_t)(t0 + lrow) * 256 + h * 32 + lk * 8];
      f4 a = (f4)(0.f);
      a = __builtin_amdgcn_mfma_f32_16x16x32_bf16(qfh[h], kh, a, 0, 0, 0);
      a = __builtin_amdgcn_mfma_f32_16x16x32_bf16(qfh[h], kl, a, 0, 0, 0);
      a = __builtin_amdgcn_mfma_f32_16x16x32_bf16(qfl[h], kh, a, 0, 0, 0);
      acc[h] = a;
    }
#pragma unroll
    for (int e = 0; e < 4; ++e) {
      int row = lt + wr * 16 + lk * 4 + e;
      int a = AD[(size_t)row * 1024 + t0 + lrow];
      bool pred = a > 0;
      float raw[8];
#pragma unroll
      for (int h = 0; h < 8; ++h) { float v = acc[h][e]; raw[h] = fmaxf(v, 0.01f * v); }
#pragma unroll
      for (int i2 = 0; i2 < 8; ++i2) {
        float s = 0.f;
#pragma unroll
        for (int j = 0; j < 8; ++j) s = fmaf(Lam[i2 * 8 + j], raw[j], s);
        float p = pred ? __expf(s - ms[e][i2]) * rs[e][i2] : 0.f;
        AT[((size_t)i2 * 1024 + row) * 1024 + t0 + lrow] = p;
      }
    }
  }
}

// ---------------- K4: PV via bf16 MFMA + GELU -> g ----------------
__global__ __launch_bounds__(256, 4) void k_pv(
    const float* __restrict__ attn, const ushort* __restrict__ vT,
    float* __restrict__ g) {
  __shared__ ushort Vs[32][136];
  __shared__ unsigned pt[64 * 128 / 2];
  int bid = blockIdx.x;
  int b = bid & 7, h = (bid >> 3) & 7, lt = (bid >> 6) * 64;
  int tid = threadIdx.x, wid = tid >> 6, lane = tid & 63;
  int lrow = lane & 15, lk = lane >> 4;
  const float* AT = attn + ((size_t)(b * 8 + h) * 1024 + lt) * 1024;
  const ushort* VTb = vT + (size_t)(b * 256 + h * 32) * 1024;
  char* ptb = (char*)pt;
  f4 acc[2];
  acc[0] = (f4)(0.f); acc[1] = (f4)(0.f);

  for (int tc = 0; tc < 1024; tc += 128) {
    {
      int col = tid >> 3, toff = (tid & 7) * 16;
      u4 v0 = *(const u4*)&VTb[(size_t)col * 1024 + tc + toff];
      u4 v1 = *(const u4*)&VTb[(size_t)col * 1024 + tc + toff + 8];
      *(u4*)&Vs[col][toff] = v0;
      *(u4*)&Vs[col][toff + 8] = v1;
    }
    {
      int row = tid >> 2, tq = (tid & 3) * 32;
      const float* src = &AT[(size_t)row * 1024 + tc + tq];
#pragma unroll
      for (int i = 0; i < 4; ++i) {
        f4 p0 = *(const f4*)&src[i * 8];
        f4 p1 = *(const f4*)&src[i * 8 + 4];
        u4 pk;
        pk.x = (unsigned)f2bf(p0[0]) | ((unsigned)f2bf(p0[1]) << 16);
        pk.y = (unsigned)f2bf(p0[2]) | ((unsigned)f2bf(p0[3]) << 16);
        pk.z = (unsigned)f2bf(p1[0]) | ((unsigned)f2bf(p1[1]) << 16);
        pk.w = (unsigned)f2bf(p1[2]) | ((unsigned)f2bf(p1[3]) << 16);
        int t = tq + i * 8;
        int boff = row * 256 + ((t * 2) ^ ((row & 7) << 4));
        *(u4*)(ptb + boff) = pk;
      }
    }
    __syncthreads();
    int prow = wid * 16 + lrow;
#pragma unroll
    for (int ks = 0; ks < 4; ++ks) {
      int t = ks * 32 + lk * 8;
      int aoff = prow * 256 + ((t * 2) ^ ((prow & 7) << 4));
      s8v af = *(const s8v*)(ptb + aoff);
#pragma unroll
      for (int nq = 0; nq < 2; ++nq) {
        s8v bf = *(const s8v*)&Vs[nq * 16 + lrow][t];
        acc[nq] = __builtin_amdgcn_mfma_f32_16x16x32_bf16(af, bf, acc[nq], 0, 0, 0);
      }
    }
    __syncthreads();
  }
#pragma unroll
  for (int nq = 0; nq < 2; ++nq)
#pragma unroll
    for (int e = 0; e < 4; ++e) {
      float v = acc[nq][e];
      float ge = 0.5f * v * (1.f + erff(v * 0.70710678118654752f));
      int row = lt + wid * 16 + lk * 4 + e;
      int col = h * 32 + nq * 16 + lrow;
      g[(size_t)(b * 1024 + row) * 256 + col] = ge;
    }
}

// ---------------- K5: out = gelu(v) @ Wproj^T (fp32, small) ----------------
__global__ __launch_bounds__(256) void k_proj(
    const float* __restrict__ g, const float* __restrict__ Wp,
    float* __restrict__ out) {
  __shared__ float g_s[16][68];
  __shared__ float w_s[16][68];
  int rt = blockIdx.y * 64;
  int it = blockIdx.x * 64;
  int tid = threadIdx.x;
  int tx = tid & 15, ty = tid >> 4;
  int r4 = tid >> 2, cq = tid & 3;
  float acc[4][4] = {};
  for (int kc = 0; kc < 256; kc += 16) {
    float4 gv = *(const float4*)&g[(size_t)(rt + r4) * 256 + kc + cq * 4];
    g_s[cq * 4 + 0][r4] = gv.x; g_s[cq * 4 + 1][r4] = gv.y;
    g_s[cq * 4 + 2][r4] = gv.z; g_s[cq * 4 + 3][r4] = gv.w;
    float4 wv = *(const float4*)&Wp[(size_t)(it + r4) * 256 + kc + cq * 4];
    w_s[cq * 4 + 0][r4] = wv.x; w_s[cq * 4 + 1][r4] = wv.y;
    w_s[cq * 4 + 2][r4] = wv.z; w_s[cq * 4 + 3][r4] = wv.w;
    __syncthreads();
#pragma unroll
    for (int k = 0; k < 16; ++k) {
      float4 a = *(const float4*)&g_s[k][ty * 4];
      float4 bb = *(const float4*)&w_s[k][tx * 4];
      acc[0][0] = fmaf(a.x, bb.x, acc[0][0]); acc[0][1] = fmaf(a.x, bb.y, acc[0][1]);
      acc[0][2] = fmaf(a.x, bb.z, acc[0][2]); acc[0][3] = fmaf(a.x, bb.w, acc[0][3]);
      acc[1][0] = fmaf(a.y, bb.x, acc[1][0]); acc[1][1] = fmaf(a.y, bb.y, acc[1][1]);
      acc[1][2] = fmaf(a.y, bb.z, acc[1][2]); acc[1][3] = fmaf(a.y, bb.w, acc[1][3]);
      acc[2][0] = fmaf(a.z, bb.x, acc[2][0]); acc[2][1] = fmaf(a.z, bb.y, acc[2][1]);
      acc[2][2] = fmaf(a.z, bb.z, acc[2][2]); acc[2][3] = fmaf(a.z, bb.w, acc[2][3]);
      acc[3][0] = fmaf(a.w, bb.x, acc[3][0]); acc[3][1] = fmaf(a.w, bb.y, acc[3][1]);
      acc[3][2] = fmaf(a.w, bb.z, acc[3][2]); acc[3][3] = fmaf(a.w, bb.w, acc[3][3]);
    }
    __syncthreads();
  }
#pragma unroll
  for (int i = 0; i < 4; ++i) {
    float4 o = make_float4(acc[i][0], acc[i][1], acc[i][2], acc[i][3]);
    *(float4*)&out[(size_t)(rt + ty * 4 + i) * 256 + it + tx * 4] = o;
  }
}

extern "C" void kernel_launch(void* const* d_in, const int* in_sizes, int n_in,
                              void* d_out, int out_size, void* d_ws, size_t ws_size,
                              hipStream_t stream) {
  const float* x   = (const float*)d_in[0];
  const int*   adj = (const int*)d_in[1];
  const float* Wq  = (const float*)d_in[3];
  const float* Wk  = (const float*)d_in[4];
  const float* Wv  = (const float*)d_in[5];
  const float* Lam = (const float*)d_in[6];
  const float* Wp  = (const float*)d_in[7];

  float* out  = (float*)d_out;                 // [8,1024,256]
  float* attn = out + (size_t)BB * TT * 256;   // [8,8,1024,1024]

  const size_t SZ = (size_t)8 * 1024 * 256;    // 2097152 elements
  char* base = (char*)d_ws;
  ushort* xTqhi = (ushort*)(base + 0 * SZ * 2);
  ushort* xTqlo = (ushort*)(base + 1 * SZ * 2);
  ushort* xTkhi = (ushort*)(base + 2 * SZ * 2);
  ushort* xTklo = (ushort*)(base + 3 * SZ * 2);
  ushort* vT    = (ushort*)(base + 4 * SZ * 2);
  ushort* qhi   = (ushort*)(base + 5 * SZ * 2);
  ushort* qlo   = (ushort*)(base + 6 * SZ * 2);
  ushort* khi   = (ushort*)(base + 7 * SZ * 2);
  ushort* klo   = (ushort*)(base + 8 * SZ * 2);
  float*  gbuf  = (float*)(base + 9 * SZ * 2);          // SZ floats (8 MB)
  float*  pm    = (float*)(base + 9 * SZ * 2 + SZ * 4); // 512K floats
  float*  ps    = pm + 524288;
  float*  fmb   = ps + 524288;                           // 65536 floats
  float*  frb   = fmb + 65536;

  k_xw<<<256, 256, 0, stream>>>(x, Wq, Wk, Wv, xTqhi, xTqlo, xTkhi, xTklo, vT);
  k_gcn<<<512, 256, 0, stream>>>(adj, xTqhi, xTqlo, xTkhi, xTklo, qhi, qlo, khi, klo);
  k_stats<<<2048, 256, 0, stream>>>(qhi, qlo, khi, klo, adj, Lam, pm, ps);
  k_reduce<<<256, 256, 0, stream>>>(pm, ps, fmb, frb);
  k_final<<<2048, 256, 0, stream>>>(qhi, qlo, khi, klo, adj, Lam, fmb, frb, attn);
  k_pv<<<1024, 256, 0, stream>>>(attn, vT, gbuf);
  k_proj<<<dim3(4, 128), 256, 0, stream>>>(gbuf, Wp, out);
}

// Round 4
// 453.379 us; speedup vs baseline: 1.8564x; 1.1360x over previous
//
#include <hip/hip_runtime.h>
#include <cmath>

#define TT 1024
#define BB 8

typedef __attribute__((ext_vector_type(4))) float f4;
typedef __attribute__((ext_vector_type(4))) unsigned int u4;
typedef __attribute__((ext_vector_type(8))) short s8v;

__device__ __forceinline__ ushort f2bf(float x) {
  unsigned u = __builtin_bit_cast(unsigned, x);
  unsigned r = (u + 0x7FFFu + ((u >> 16) & 1u)) >> 16;
  return (ushort)r;
}
__device__ __forceinline__ float bf2f(ushort b) {
  unsigned u = ((unsigned)b) << 16;
  return __builtin_bit_cast(float, u);
}
__device__ __forceinline__ void st8(ushort* p, const ushort* v) {
  u4 w;
  w.x = (unsigned)v[0] | ((unsigned)v[1] << 16);
  w.y = (unsigned)v[2] | ((unsigned)v[3] << 16);
  w.z = (unsigned)v[4] | ((unsigned)v[5] << 16);
  w.w = (unsigned)v[6] | ((unsigned)v[7] << 16);
  *(u4*)p = w;
}

// ---------------- K1: x @ {Wq/16, Wk, Wv} -> transposed bf16 hi/lo + vT ----------------
// grid 512: b=bid&7, 16-token tiles. 2 waves/EU min.
__global__ __launch_bounds__(256, 2) void k_xw(
    const float* __restrict__ x, const float* __restrict__ Wq,
    const float* __restrict__ Wk, const float* __restrict__ Wv,
    ushort* __restrict__ xTqhi, ushort* __restrict__ xTqlo,
    ushort* __restrict__ xTkhi, ushort* __restrict__ xTklo,
    ushort* __restrict__ vT) {
  __shared__ float xs[16][256];
  int bid = blockIdx.x;
  int b = bid & 7, t0 = (bid >> 3) * 16;
  int tid = threadIdx.x;
#pragma unroll
  for (int i = 0; i < 4; ++i) {
    int e = i * 256 + tid;
    int t = e >> 6, c4 = (e & 63) * 4;
    *(f4*)&xs[t][c4] = *(const f4*)&x[((size_t)(b * 1024 + t0 + t)) * 256 + c4];
  }
  int c = tid, h = c >> 5, d = c & 31;
  float wqr[32], wkr[32], wvr[32];
#pragma unroll
  for (int e = 0; e < 32; ++e) {
    wqr[e] = Wq[e * 32 + d] * 0.0625f;  // fold scale = dim^-0.5 = 1/16 into Wq
    wkr[e] = Wk[e * 32 + d];
    wvr[e] = Wv[e * 32 + d];
  }
  __syncthreads();
  size_t rowq = ((size_t)(b * 256 + c)) * 1024 + t0;
#pragma unroll
  for (int tg = 0; tg < 2; ++tg) {
    ushort qh[8], ql[8], kh[8], kl[8], vh[8];
#pragma unroll
    for (int tt = 0; tt < 8; ++tt) {
      int t = tg * 8 + tt;
      float aq = 0.f, ak = 0.f, av = 0.f;
#pragma unroll
      for (int e = 0; e < 32; ++e) {
        float xe = xs[t][h * 32 + e];
        aq = fmaf(xe, wqr[e], aq);
        ak = fmaf(xe, wkr[e], ak);
        av = fmaf(xe, wvr[e], av);
      }
      ushort hq = f2bf(aq); qh[tt] = hq; ql[tt] = f2bf(aq - bf2f(hq));
      ushort hk = f2bf(ak); kh[tt] = hk; kl[tt] = f2bf(ak - bf2f(hk));
      vh[tt] = f2bf(av);
    }
    st8(xTqhi + rowq + tg * 8, qh);
    st8(xTqlo + rowq + tg * 8, ql);
    st8(xTkhi + rowq + tg * 8, kh);
    st8(xTklo + rowq + tg * 8, kl);
    st8(vT    + rowq + tg * 8, vh);
  }
}

// ---------------- K2: GCN [q|k] = adj @ [xq|xk] via MFMA, grid 512 ----------------
__global__ __launch_bounds__(256, 2) void k_gcn(
    const int* __restrict__ adj,
    const ushort* __restrict__ xTqhi, const ushort* __restrict__ xTqlo,
    const ushort* __restrict__ xTkhi, const ushort* __restrict__ xTklo,
    ushort* __restrict__ qhi, ushort* __restrict__ qlo,
    ushort* __restrict__ khi, ushort* __restrict__ klo) {
  int bid = blockIdx.x;
  int ct = bid & 3, lt = ((bid >> 2) & 15) * 64, b = bid >> 6;
  int nt = ct >> 1, cbase = (ct & 1) * 128;
  const ushort* XH = (nt ? xTkhi : xTqhi) + (size_t)b * 256 * 1024;
  const ushort* XL = (nt ? xTklo : xTqlo) + (size_t)b * 256 * 1024;
  ushort* OH = (nt ? khi : qhi) + (size_t)b * 1024 * 256;
  ushort* OL = (nt ? klo : qlo) + (size_t)b * 1024 * 256;
  const int* AD = adj + (size_t)b * 1024 * 1024;
  int tid = threadIdx.x, wid = tid >> 6, lane = tid & 63;
  int lrow = lane & 15, lk = lane >> 4;
  int wr = wid >> 1, wc = wid & 1;
  int rbase = lt + wr * 32;
  int cb2 = cbase + wc * 64;
  f4 acc[2][4];
#pragma unroll
  for (int i = 0; i < 2; ++i)
#pragma unroll
    for (int j = 0; j < 4; ++j) acc[i][j] = (f4)(0.f);

  for (int k0 = 0; k0 < 1024; k0 += 32) {
    s8v afr[2];
#pragma unroll
    for (int rq = 0; rq < 2; ++rq) {
      const int* ap = &AD[(size_t)(rbase + rq * 16 + lrow) * 1024 + k0 + lk * 8];
      int4 a0 = *(const int4*)ap;
      int4 a1 = *(const int4*)(ap + 4);
      u4 fw;
      fw.x = (a0.x ? 0x3F80u : 0u) | (a0.y ? 0x3F800000u : 0u);
      fw.y = (a0.z ? 0x3F80u : 0u) | (a0.w ? 0x3F800000u : 0u);
      fw.z = (a1.x ? 0x3F80u : 0u) | (a1.y ? 0x3F800000u : 0u);
      fw.w = (a1.z ? 0x3F80u : 0u) | (a1.w ? 0x3F800000u : 0u);
      afr[rq] = __builtin_bit_cast(s8v, fw);
    }
#pragma unroll
    for (int nq = 0; nq < 4; ++nq) {
      int col = cb2 + nq * 16 + lrow;
      s8v bh = *(const s8v*)&XH[(size_t)col * 1024 + k0 + lk * 8];
      s8v bl = *(const s8v*)&XL[(size_t)col * 1024 + k0 + lk * 8];
#pragma unroll
      for (int rq = 0; rq < 2; ++rq) {
        acc[rq][nq] = __builtin_amdgcn_mfma_f32_16x16x32_bf16(afr[rq], bh, acc[rq][nq], 0, 0, 0);
        acc[rq][nq] = __builtin_amdgcn_mfma_f32_16x16x32_bf16(afr[rq], bl, acc[rq][nq], 0, 0, 0);
      }
    }
  }
#pragma unroll
  for (int rq = 0; rq < 2; ++rq)
#pragma unroll
    for (int nq = 0; nq < 4; ++nq)
#pragma unroll
      for (int e = 0; e < 4; ++e) {
        float v = acc[rq][nq][e];
        int row = rbase + rq * 16 + lk * 4 + e;
        int col = cb2 + nq * 16 + lrow;
        ushort hi = f2bf(v);
        ushort lo = f2bf(v - bf2f(hi));
        OH[(size_t)row * 256 + col] = hi;
        OL[(size_t)row * 256 + col] = lo;
      }
}

// ---------------- K3a: score stats, grid 2048 (b x 32 row-tiles x 8 col-chunks) --------
__global__ __launch_bounds__(256, 2) void k_stats(
    const ushort* __restrict__ qhi, const ushort* __restrict__ qlo,
    const ushort* __restrict__ khi, const ushort* __restrict__ klo,
    const int* __restrict__ adj, const float* __restrict__ Lam,
    float* __restrict__ pm, float* __restrict__ ps) {
  __shared__ float sm_m[2][32][8];
  __shared__ float sm_s[2][32][8];
  int bid = blockIdx.x;
  int b = bid >> 8;
  int lt = ((bid >> 3) & 31) << 5;
  int tc = bid & 7;
  int tid = threadIdx.x, wid = tid >> 6, lane = tid & 63;
  int lrow = lane & 15, lk = lane >> 4;
  int wr = wid >> 1, wc = wid & 1;
  const ushort* QH = qhi + (size_t)b * 1024 * 256;
  const ushort* QL = qlo + (size_t)b * 1024 * 256;
  const ushort* KH = khi + (size_t)b * 1024 * 256;
  const ushort* KL = klo + (size_t)b * 1024 * 256;
  const int* AD = adj + (size_t)b * 1024 * 1024;

  s8v qfh[8], qfl[8];
  int qrow = lt + wr * 16 + lrow;
#pragma unroll
  for (int h = 0; h < 8; ++h) {
    qfh[h] = *(const s8v*)&QH[(size_t)qrow * 256 + h * 32 + lk * 8];
    qfl[h] = *(const s8v*)&QL[(size_t)qrow * 256 + h * 32 + lk * 8];
  }
  float ms[4][8], ss[4][8];
#pragma unroll
  for (int e = 0; e < 4; ++e)
#pragma unroll
    for (int i2 = 0; i2 < 8; ++i2) { ms[e][i2] = -3.0e38f; ss[e][i2] = 0.f; }

  for (int it = 0; it < 4; ++it) {
    int t0 = tc * 128 + (it * 2 + wc) * 16;
    f4 acc[8];
#pragma unroll
    for (int h = 0; h < 8; ++h) {
      s8v kh = *(const s8v*)&KH[(size_t)(t0 + lrow) * 256 + h * 32 + lk * 8];
      s8v kl = *(const s8v*)&KL[(size_t)(t0 + lrow) * 256 + h * 32 + lk * 8];
      f4 a = (f4)(0.f);
      a = __builtin_amdgcn_mfma_f32_16x16x32_bf16(qfh[h], kh, a, 0, 0, 0);
      a = __builtin_amdgcn_mfma_f32_16x16x32_bf16(qfh[h], kl, a, 0, 0, 0);
      a = __builtin_amdgcn_mfma_f32_16x16x32_bf16(qfl[h], kh, a, 0, 0, 0);
      acc[h] = a;
    }
#pragma unroll
    for (int e = 0; e < 4; ++e) {
      int row = lt + wr * 16 + lk * 4 + e;
      int a = AD[(size_t)row * 1024 + t0 + lrow];
      bool pred = a > 0;
      float raw[8];
#pragma unroll
      for (int h = 0; h < 8; ++h) { float v = acc[h][e]; raw[h] = fmaxf(v, 0.01f * v); }
#pragma unroll
      for (int i2 = 0; i2 < 8; ++i2) {
        float s = 0.f;
#pragma unroll
        for (int j = 0; j < 8; ++j) s = fmaf(Lam[i2 * 8 + j], raw[j], s);
        float d = s - ms[e][i2];
        float ex = __expf(fminf(d, -d));
        float snew = (d > 0.f) ? fmaf(ss[e][i2], ex, 1.f) : (ss[e][i2] + ex);
        float mnew = fmaxf(ms[e][i2], s);
        if (pred) { ss[e][i2] = snew; ms[e][i2] = mnew; }
      }
    }
  }
  // reduce across the 16 col-lanes (bits 0..3 of lane)
#pragma unroll
  for (int e = 0; e < 4; ++e)
#pragma unroll
    for (int i2 = 0; i2 < 8; ++i2) {
      float mm = ms[e][i2], sv = ss[e][i2];
      for (int off = 1; off < 16; off <<= 1) {
        float om = __shfl_xor(mm, off, 64);
        float os = __shfl_xor(sv, off, 64);
        float d = mm - om;
        float ex = __expf(fminf(d, -d));
        float sA = fmaf(os, ex, sv);
        float sB = fmaf(sv, ex, os);
        sv = (d >= 0.f) ? sA : sB;
        mm = fmaxf(mm, om);
      }
      ms[e][i2] = mm; ss[e][i2] = sv;
    }
  if (lrow == 0) {
#pragma unroll
    for (int e = 0; e < 4; ++e)
#pragma unroll
      for (int i2 = 0; i2 < 8; ++i2) {
        sm_m[wc][wr * 16 + lk * 4 + e][i2] = ms[e][i2];
        sm_s[wc][wr * 16 + lk * 4 + e][i2] = ss[e][i2];
      }
  }
  __syncthreads();
  {
    int rw = tid >> 3, i2 = tid & 7;
    float m0 = sm_m[0][rw][i2], m1 = sm_m[1][rw][i2];
    float s0 = sm_s[0][rw][i2], s1 = sm_s[1][rw][i2];
    float M = fmaxf(m0, m1);
    float S = s0 * __expf(m0 - M) + s1 * __expf(m1 - M);
    size_t R = ((size_t)(b * 8 + i2) * 1024 + lt + rw);
    pm[R * 8 + tc] = M;
    ps[R * 8 + tc] = S;
  }
}

// ---------------- K3b: reduce 8 chunk-partials -> (m, 1/sum) per row ----------------
__global__ __launch_bounds__(256) void k_reduce(
    const float* __restrict__ pm, const float* __restrict__ ps,
    float* __restrict__ fm, float* __restrict__ fr) {
  int R = blockIdx.x * 256 + threadIdx.x;   // 65536 rows
  f4 m0 = *(const f4*)&pm[(size_t)R * 8];
  f4 m1 = *(const f4*)&pm[(size_t)R * 8 + 4];
  f4 s0 = *(const f4*)&ps[(size_t)R * 8];
  f4 s1 = *(const f4*)&ps[(size_t)R * 8 + 4];
  float M = fmaxf(fmaxf(fmaxf(m0.x, m0.y), fmaxf(m0.z, m0.w)),
                  fmaxf(fmaxf(m1.x, m1.y), fmaxf(m1.z, m1.w)));
  float S = s0.x * __expf(m0.x - M) + s0.y * __expf(m0.y - M) +
            s0.z * __expf(m0.z - M) + s0.w * __expf(m0.w - M) +
            s1.x * __expf(m1.x - M) + s1.y * __expf(m1.y - M) +
            s1.z * __expf(m1.z - M) + s1.w * __expf(m1.w - M);
  fm[R] = M;
  fr[R] = 1.f / S;
}

// ---------------- K3c: recompute scores + write final softmax p, grid 2048 ----------
__global__ __launch_bounds__(256, 2) void k_final(
    const ushort* __restrict__ qhi, const ushort* __restrict__ qlo,
    const ushort* __restrict__ khi, const ushort* __restrict__ klo,
    const int* __restrict__ adj, const float* __restrict__ Lam,
    const float* __restrict__ fm, const float* __restrict__ fr,
    float* __restrict__ attn) {
  __shared__ float fin_m[32][8];
  __shared__ float fin_r[32][8];
  int bid = blockIdx.x;
  int b = bid >> 8;
  int lt = ((bid >> 3) & 31) << 5;
  int tc = bid & 7;
  int tid = threadIdx.x, wid = tid >> 6, lane = tid & 63;
  int lrow = lane & 15, lk = lane >> 4;
  int wr = wid >> 1, wc = wid & 1;
  const ushort* QH = qhi + (size_t)b * 1024 * 256;
  const ushort* QL = qlo + (size_t)b * 1024 * 256;
  const ushort* KH = khi + (size_t)b * 1024 * 256;
  const ushort* KL = klo + (size_t)b * 1024 * 256;
  const int* AD = adj + (size_t)b * 1024 * 1024;
  float* AT = attn + (size_t)b * 8 * 1024 * 1024;
  {
    int rw = tid >> 3, i2 = tid & 7;
    size_t R = ((size_t)(b * 8 + i2) * 1024 + lt + rw);
    fin_m[rw][i2] = fm[R];
    fin_r[rw][i2] = fr[R];
  }
  s8v qfh[8], qfl[8];
  int qrow = lt + wr * 16 + lrow;
#pragma unroll
  for (int h = 0; h < 8; ++h) {
    qfh[h] = *(const s8v*)&QH[(size_t)qrow * 256 + h * 32 + lk * 8];
    qfl[h] = *(const s8v*)&QL[(size_t)qrow * 256 + h * 32 + lk * 8];
  }
  __syncthreads();
  float ms[4][8], rs[4][8];
#pragma unroll
  for (int e = 0; e < 4; ++e)
#pragma unroll
    for (int i2 = 0; i2 < 8; ++i2) {
      ms[e][i2] = fin_m[wr * 16 + lk * 4 + e][i2];
      rs[e][i2] = fin_r[wr * 16 + lk * 4 + e][i2];
    }
  for (int it = 0; it < 4; ++it) {
    int t0 = tc * 128 + (it * 2 + wc) * 16;
    f4 acc[8];
#pragma unroll
    for (int h = 0; h < 8; ++h) {
      s8v kh = *(const s8v*)&KH[(size_t)(t0 + lrow) * 256 + h * 32 + lk * 8];
      s8v kl = *(const s8v*)&KL[(size_t)(t0 + lrow) * 256 + h * 32 + lk * 8];
      f4 a = (f4)(0.f);
      a = __builtin_amdgcn_mfma_f32_16x16x32_bf16(qfh[h], kh, a, 0, 0, 0);
      a = __builtin_amdgcn_mfma_f32_16x16x32_bf16(qfh[h], kl, a, 0, 0, 0);
      a = __builtin_amdgcn_mfma_f32_16x16x32_bf16(qfl[h], kh, a, 0, 0, 0);
      acc[h] = a;
    }
#pragma unroll
    for (int e = 0; e < 4; ++e) {
      int row = lt + wr * 16 + lk * 4 + e;
      int a = AD[(size_t)row * 1024 + t0 + lrow];
      bool pred = a > 0;
      float raw[8];
#pragma unroll
      for (int h = 0; h < 8; ++h) { float v = acc[h][e]; raw[h] = fmaxf(v, 0.01f * v); }
#pragma unroll
      for (int i2 = 0; i2 < 8; ++i2) {
        float s = 0.f;
#pragma unroll
        for (int j = 0; j < 8; ++j) s = fmaf(Lam[i2 * 8 + j], raw[j], s);
        float p = pred ? __expf(s - ms[e][i2]) * rs[e][i2] : 0.f;
        AT[((size_t)i2 * 1024 + row) * 1024 + t0 + lrow] = p;
      }
    }
  }
}

// ---------------- K4: PV via bf16 MFMA + GELU -> g ----------------
__global__ __launch_bounds__(256, 4) void k_pv(
    const float* __restrict__ attn, const ushort* __restrict__ vT,
    float* __restrict__ g) {
  __shared__ ushort Vs[32][136];
  __shared__ unsigned pt[64 * 128 / 2];
  int bid = blockIdx.x;
  int b = bid & 7, h = (bid >> 3) & 7, lt = (bid >> 6) * 64;
  int tid = threadIdx.x, wid = tid >> 6, lane = tid & 63;
  int lrow = lane & 15, lk = lane >> 4;
  const float* AT = attn + ((size_t)(b * 8 + h) * 1024 + lt) * 1024;
  const ushort* VTb = vT + (size_t)(b * 256 + h * 32) * 1024;
  char* ptb = (char*)pt;
  f4 acc[2];
  acc[0] = (f4)(0.f); acc[1] = (f4)(0.f);

  for (int tc = 0; tc < 1024; tc += 128) {
    {
      int col = tid >> 3, toff = (tid & 7) * 16;
      u4 v0 = *(const u4*)&VTb[(size_t)col * 1024 + tc + toff];
      u4 v1 = *(const u4*)&VTb[(size_t)col * 1024 + tc + toff + 8];
      *(u4*)&Vs[col][toff] = v0;
      *(u4*)&Vs[col][toff + 8] = v1;
    }
    {
      int row = tid >> 2, tq = (tid & 3) * 32;
      const float* src = &AT[(size_t)row * 1024 + tc + tq];
#pragma unroll
      for (int i = 0; i < 4; ++i) {
        f4 p0 = *(const f4*)&src[i * 8];
        f4 p1 = *(const f4*)&src[i * 8 + 4];
        u4 pk;
        pk.x = (unsigned)f2bf(p0[0]) | ((unsigned)f2bf(p0[1]) << 16);
        pk.y = (unsigned)f2bf(p0[2]) | ((unsigned)f2bf(p0[3]) << 16);
        pk.z = (unsigned)f2bf(p1[0]) | ((unsigned)f2bf(p1[1]) << 16);
        pk.w = (unsigned)f2bf(p1[2]) | ((unsigned)f2bf(p1[3]) << 16);
        int t = tq + i * 8;
        int boff = row * 256 + ((t * 2) ^ ((row & 7) << 4));
        *(u4*)(ptb + boff) = pk;
      }
    }
    __syncthreads();
    int prow = wid * 16 + lrow;
#pragma unroll
    for (int ks = 0; ks < 4; ++ks) {
      int t = ks * 32 + lk * 8;
      int aoff = prow * 256 + ((t * 2) ^ ((prow & 7) << 4));
      s8v af = *(const s8v*)(ptb + aoff);
#pragma unroll
      for (int nq = 0; nq < 2; ++nq) {
        s8v bf = *(const s8v*)&Vs[nq * 16 + lrow][t];
        acc[nq] = __builtin_amdgcn_mfma_f32_16x16x32_bf16(af, bf, acc[nq], 0, 0, 0);
      }
    }
    __syncthreads();
  }
#pragma unroll
  for (int nq = 0; nq < 2; ++nq)
#pragma unroll
    for (int e = 0; e < 4; ++e) {
      float v = acc[nq][e];
      float ge = 0.5f * v * (1.f + erff(v * 0.70710678118654752f));
      int row = lt + wid * 16 + lk * 4 + e;
      int col = h * 32 + nq * 16 + lrow;
      g[(size_t)(b * 1024 + row) * 256 + col] = ge;
    }
}

// ---------------- K5: out = gelu(v) @ Wproj^T (fp32, small) ----------------
__global__ __launch_bounds__(256, 2) void k_proj(
    const float* __restrict__ g, const float* __restrict__ Wp,
    float* __restrict__ out) {
  __shared__ float g_s[16][68];
  __shared__ float w_s[16][68];
  int rt = blockIdx.y * 64;
  int it = blockIdx.x * 64;
  int tid = threadIdx.x;
  int tx = tid & 15, ty = tid >> 4;
  int r4 = tid >> 2, cq = tid & 3;
  float acc[4][4] = {};
  for (int kc = 0; kc < 256; kc += 16) {
    float4 gv = *(const float4*)&g[(size_t)(rt + r4) * 256 + kc + cq * 4];
    g_s[cq * 4 + 0][r4] = gv.x; g_s[cq * 4 + 1][r4] = gv.y;
    g_s[cq * 4 + 2][r4] = gv.z; g_s[cq * 4 + 3][r4] = gv.w;
    float4 wv = *(const float4*)&Wp[(size_t)(it + r4) * 256 + kc + cq * 4];
    w_s[cq * 4 + 0][r4] = wv.x; w_s[cq * 4 + 1][r4] = wv.y;
    w_s[cq * 4 + 2][r4] = wv.z; w_s[cq * 4 + 3][r4] = wv.w;
    __syncthreads();
#pragma unroll
    for (int k = 0; k < 16; ++k) {
      float4 a = *(const float4*)&g_s[k][ty * 4];
      float4 bb = *(const float4*)&w_s[k][tx * 4];
      acc[0][0] = fmaf(a.x, bb.x, acc[0][0]); acc[0][1] = fmaf(a.x, bb.y, acc[0][1]);
      acc[0][2] = fmaf(a.x, bb.z, acc[0][2]); acc[0][3] = fmaf(a.x, bb.w, acc[0][3]);
      acc[1][0] = fmaf(a.y, bb.x, acc[1][0]); acc[1][1] = fmaf(a.y, bb.y, acc[1][1]);
      acc[1][2] = fmaf(a.y, bb.z, acc[1][2]); acc[1][3] = fmaf(a.y, bb.w, acc[1][3]);
      acc[2][0] = fmaf(a.z, bb.x, acc[2][0]); acc[2][1] = fmaf(a.z, bb.y, acc[2][1]);
      acc[2][2] = fmaf(a.z, bb.z, acc[2][2]); acc[2][3] = fmaf(a.z, bb.w, acc[2][3]);
      acc[3][0] = fmaf(a.w, bb.x, acc[3][0]); acc[3][1] = fmaf(a.w, bb.y, acc[3][1]);
      acc[3][2] = fmaf(a.w, bb.z, acc[3][2]); acc[3][3] = fmaf(a.w, bb.w, acc[3][3]);
    }
    __syncthreads();
  }
#pragma unroll
  for (int i = 0; i < 4; ++i) {
    float4 o = make_float4(acc[i][0], acc[i][1], acc[i][2], acc[i][3]);
    *(float4*)&out[(size_t)(rt + ty * 4 + i) * 256 + it + tx * 4] = o;
  }
}

extern "C" void kernel_launch(void* const* d_in, const int* in_sizes, int n_in,
                              void* d_out, int out_size, void* d_ws, size_t ws_size,
                              hipStream_t stream) {
  const float* x   = (const float*)d_in[0];
  const int*   adj = (const int*)d_in[1];
  const float* Wq  = (const float*)d_in[3];
  const float* Wk  = (const float*)d_in[4];
  const float* Wv  = (const float*)d_in[5];
  const float* Lam = (const float*)d_in[6];
  const float* Wp  = (const float*)d_in[7];

  float* out  = (float*)d_out;                 // [8,1024,256]
  float* attn = out + (size_t)BB * TT * 256;   // [8,8,1024,1024]

  const size_t SZ = (size_t)8 * 1024 * 256;    // 2097152 elements
  char* base = (char*)d_ws;
  ushort* xTqhi = (ushort*)(base + 0 * SZ * 2);
  ushort* xTqlo = (ushort*)(base + 1 * SZ * 2);
  ushort* xTkhi = (ushort*)(base + 2 * SZ * 2);
  ushort* xTklo = (ushort*)(base + 3 * SZ * 2);
  ushort* vT    = (ushort*)(base + 4 * SZ * 2);
  ushort* qhi   = (ushort*)(base + 5 * SZ * 2);
  ushort* qlo   = (ushort*)(base + 6 * SZ * 2);
  ushort* khi   = (ushort*)(base + 7 * SZ * 2);
  ushort* klo   = (ushort*)(base + 8 * SZ * 2);
  float*  gbuf  = (float*)(base + 9 * SZ * 2);          // SZ floats (8 MB)
  float*  pm    = (float*)(base + 9 * SZ * 2 + SZ * 4); // 512K floats
  float*  ps    = pm + 524288;
  float*  fmb   = ps + 524288;                           // 65536 floats
  float*  frb   = fmb + 65536;

  k_xw<<<512, 256, 0, stream>>>(x, Wq, Wk, Wv, xTqhi, xTqlo, xTkhi, xTklo, vT);
  k_gcn<<<512, 256, 0, stream>>>(adj, xTqhi, xTqlo, xTkhi, xTklo, qhi, qlo, khi, klo);
  k_stats<<<2048, 256, 0, stream>>>(qhi, qlo, khi, klo, adj, Lam, pm, ps);
  k_reduce<<<256, 256, 0, stream>>>(pm, ps, fmb, frb);
  k_final<<<2048, 256, 0, stream>>>(qhi, qlo, khi, klo, adj, Lam, fmb, frb, attn);
  k_pv<<<1024, 256, 0, stream>>>(attn, vT, gbuf);
  k_proj<<<dim3(4, 128), 256, 0, stream>>>(gbuf, Wp, out);
}